// Round 1
// baseline (771.383 us; speedup 1.0000x reference)
//
#include <hip/hip_runtime.h>

#define NUM_NODES 100000
#define HIDDEN 128
#define NPAIRS 1000000

constexpr int BP = 128;   // pairs per block
constexpr int KT = 32;    // k-tile depth

// Detect whether node_pairs is int64 (odd dwords == high words == 0) or int32.
__global__ void detect_idx64(const unsigned int* __restrict__ raw, int* __restrict__ flag) {
  if (threadIdx.x == 0 && blockIdx.x == 0) {
    int is64 = 1;
    for (int i = 1; i < 128; i += 2) {
      if (raw[i] != 0u) { is64 = 0; break; }
    }
    *flag = is64;
  }
}

__global__ __launch_bounds__(256) void edge_mlp(
    const float* __restrict__ z,
    const void*  __restrict__ pairs,
    const float* __restrict__ W1,
    const float* __restrict__ b1,
    const float* __restrict__ W2,
    const float* __restrict__ b2,
    const int*   __restrict__ flag,
    float*       __restrict__ out)
{
  __shared__ __align__(16) float As[KT][BP];      // 16 KB, [k][pair]
  __shared__ __align__(16) float Bs[KT][HIDDEN];  // 16 KB, [k][col]

  const int tid = threadIdx.x;
  const int p0  = blockIdx.x * BP;
  const int is64 = *flag;

  // --- staging roles ---
  const int sp   = tid >> 1;        // pair row this thread stages (0..127)
  const int half = tid & 1;         // which 16-float half of the 32-k chunk
  const int bk   = tid >> 3;        // W1 row within k-tile (0..31)
  const int bc   = (tid & 7) * 16;  // W1 col start (0..112)

  int uu = 0, vv = 0;
  {
    int gp = p0 + sp;
    if (gp < NPAIRS) {
      if (is64) {
        const long long* q = (const long long*)pairs;
        uu = (int)q[2 * gp];
        vv = (int)q[2 * gp + 1];
      } else {
        const int* q = (const int*)pairs;
        uu = q[2 * gp];
        vv = q[2 * gp + 1];
      }
    }
  }

  // --- compute roles: 2x2 wave tiling, 8x8 register block per lane ---
  const int wave  = tid >> 6;
  const int lane  = tid & 63;
  const int pg    = lane >> 3;                  // 0..7
  const int cg    = lane & 7;                   // 0..7
  const int pbase = (wave >> 1) * 64 + pg * 8;  // block-local pair base
  const int cbase = (wave & 1)  * 64 + cg * 8;  // col base

  float acc[8][8];
  #pragma unroll
  for (int i = 0; i < 8; ++i)
    #pragma unroll
    for (int j = 0; j < 8; ++j) acc[i][j] = 0.f;

  for (int kt = 0; kt < 8; ++kt) {
    // stage A (gathered z rows), transposed into [k][pair]
    {
      const int node = (kt < 4) ? uu : vv;
      const int koff = (kt & 3) * 32 + half * 16;
      const float4* src = (const float4*)(z + (size_t)node * HIDDEN + koff);
      #pragma unroll
      for (int i = 0; i < 4; ++i) {
        float4 v4 = src[i];
        int tk = half * 16 + 4 * i;
        As[tk + 0][sp] = v4.x;
        As[tk + 1][sp] = v4.y;
        As[tk + 2][sp] = v4.z;
        As[tk + 3][sp] = v4.w;
      }
    }
    // stage B (W1 k-slab), contiguous
    {
      const float4* src = (const float4*)(W1 + (size_t)(kt * KT + bk) * HIDDEN + bc);
      float4* dst = (float4*)&Bs[bk][bc];
      #pragma unroll
      for (int i = 0; i < 4; ++i) dst[i] = src[i];
    }
    __syncthreads();

    #pragma unroll 8
    for (int k = 0; k < KT; ++k) {
      float4 a0  = *(const float4*)&As[k][pbase];
      float4 a1  = *(const float4*)&As[k][pbase + 4];
      float4 bb0 = *(const float4*)&Bs[k][cbase];
      float4 bb1 = *(const float4*)&Bs[k][cbase + 4];
      float av[8] = {a0.x, a0.y, a0.z, a0.w, a1.x, a1.y, a1.z, a1.w};
      float bv[8] = {bb0.x, bb0.y, bb0.z, bb0.w, bb1.x, bb1.y, bb1.z, bb1.w};
      #pragma unroll
      for (int i = 0; i < 8; ++i)
        #pragma unroll
        for (int j = 0; j < 8; ++j)
          acc[i][j] = fmaf(av[i], bv[j], acc[i][j]);
    }
    __syncthreads();
  }

  // --- fused epilogue: relu(acc + b1) . W2 + b2, reduce across col-groups ---
  float b1v[8], w2v[8];
  #pragma unroll
  for (int j = 0; j < 8; ++j) {
    b1v[j] = b1[cbase + j];
    w2v[j] = W2[cbase + j];
  }
  float psum[8];
  #pragma unroll
  for (int i = 0; i < 8; ++i) {
    float s = 0.f;
    #pragma unroll
    for (int j = 0; j < 8; ++j) {
      float h = fmaxf(acc[i][j] + b1v[j], 0.f);
      s = fmaf(h, w2v[j], s);
    }
    psum[i] = s;
  }

  float* red = &As[0][0];                 // reuse As: 128 pairs x 16 partials
  const int cidx = (wave & 1) * 8 + cg;   // 0..15
  #pragma unroll
  for (int i = 0; i < 8; ++i) red[(pbase + i) * 16 + cidx] = psum[i];
  __syncthreads();

  if (tid < BP) {
    float s = b2[0];
    #pragma unroll
    for (int j = 0; j < 16; ++j) s += red[tid * 16 + j];
    int gp = p0 + tid;
    if (gp < NPAIRS) out[gp] = s;
  }
}

extern "C" void kernel_launch(void* const* d_in, const int* in_sizes, int n_in,
                              void* d_out, int out_size, void* d_ws, size_t ws_size,
                              hipStream_t stream) {
  const float* z     = (const float*)d_in[0];
  const void*  pairs =               d_in[1];
  const float* W1    = (const float*)d_in[2];
  const float* b1    = (const float*)d_in[3];
  const float* W2    = (const float*)d_in[4];
  const float* b2    = (const float*)d_in[5];
  float* out = (float*)d_out;
  int*   flag = (int*)d_ws;

  detect_idx64<<<1, 64, 0, stream>>>((const unsigned int*)pairs, flag);
  const int grid = (NPAIRS + BP - 1) / BP;
  edge_mlp<<<grid, 256, 0, stream>>>(z, pairs, W1, b1, W2, b2, flag, out);
}

// Round 4
// 307.344 us; speedup vs baseline: 2.5098x; 2.5098x over previous
//
#include <hip/hip_runtime.h>

#define NUM_NODES 100000
#define HIDDEN 128
#define NPAIRS 1000000

constexpr int BP = 128;   // pairs per block (fallback kernel)
constexpr int KT = 32;    // k-tile depth

// ---------- idx dtype detection (int64 vs int32) ----------
__global__ void detect_idx64(const unsigned int* __restrict__ raw, int* __restrict__ flag) {
  if (threadIdx.x == 0 && blockIdx.x == 0) {
    int is64 = 1;
    for (int i = 1; i < 128; i += 2) {
      if (raw[i] != 0u) { is64 = 0; break; }
    }
    *flag = is64;
  }
}

// ---------- kernel 1: R[n, 0:128]=z[n]@W1[:128], R[n,128:256]=z[n]@W1[128:] ----------
__global__ __launch_bounds__(256) void node_precompute(
    const float* __restrict__ z,
    const float* __restrict__ W1,
    float*       __restrict__ R)
{
  __shared__ __align__(16) float As[KT][128];
  __shared__ __align__(16) float Bs[KT][128];

  const int tid = threadIdx.x;
  const int m0  = blockIdx.x * 128;
  const int hsel = blockIdx.y;          // 0 -> P (W1 rows 0..127), 1 -> Q (rows 128..255)

  const int sp   = tid >> 1;            // z row staged
  const int half = tid & 1;
  const int bk   = tid >> 3;            // W1 row within k-tile
  const int bc   = (tid & 7) * 16;

  const int zrow = (m0 + sp < NUM_NODES) ? (m0 + sp) : 0;

  const int wave  = tid >> 6;
  const int lane  = tid & 63;
  const int pg    = lane >> 3;
  const int cg    = lane & 7;
  const int pbase = (wave >> 1) * 64 + pg * 8;
  const int cbase = (wave & 1)  * 64 + cg * 8;

  float acc[8][8];
  #pragma unroll
  for (int i = 0; i < 8; ++i)
    #pragma unroll
    for (int j = 0; j < 8; ++j) acc[i][j] = 0.f;

  for (int kt = 0; kt < 4; ++kt) {
    {
      const float4* src = (const float4*)(z + (size_t)zrow * HIDDEN + kt * KT + half * 16);
      #pragma unroll
      for (int i = 0; i < 4; ++i) {
        float4 v4 = src[i];
        int tk = half * 16 + 4 * i;
        As[tk + 0][sp] = v4.x;
        As[tk + 1][sp] = v4.y;
        As[tk + 2][sp] = v4.z;
        As[tk + 3][sp] = v4.w;
      }
    }
    {
      const float4* src = (const float4*)(W1 + (size_t)(hsel * 128 + kt * KT + bk) * HIDDEN + bc);
      float4* dst = (float4*)&Bs[bk][bc];
      #pragma unroll
      for (int i = 0; i < 4; ++i) dst[i] = src[i];
    }
    __syncthreads();

    #pragma unroll 8
    for (int k = 0; k < KT; ++k) {
      float4 a0  = *(const float4*)&As[k][pbase];
      float4 a1  = *(const float4*)&As[k][pbase + 4];
      float4 bb0 = *(const float4*)&Bs[k][cbase];
      float4 bb1 = *(const float4*)&Bs[k][cbase + 4];
      float av[8] = {a0.x, a0.y, a0.z, a0.w, a1.x, a1.y, a1.z, a1.w};
      float bv[8] = {bb0.x, bb0.y, bb0.z, bb0.w, bb1.x, bb1.y, bb1.z, bb1.w};
      #pragma unroll
      for (int i = 0; i < 8; ++i)
        #pragma unroll
        for (int j = 0; j < 8; ++j)
          acc[i][j] = fmaf(av[i], bv[j], acc[i][j]);
    }
    __syncthreads();
  }

  #pragma unroll
  for (int i = 0; i < 8; ++i) {
    int r = m0 + pbase + i;
    if (r < NUM_NODES) {
      float4* dst = (float4*)(R + (size_t)r * 256 + hsel * 128 + cbase);
      dst[0] = make_float4(acc[i][0], acc[i][1], acc[i][2], acc[i][3]);
      dst[1] = make_float4(acc[i][4], acc[i][5], acc[i][6], acc[i][7]);
    }
  }
}

// ---------- kernel 2: per-edge fused relu + dot ----------
__global__ __launch_bounds__(256) void edge_pass(
    const float* __restrict__ R,
    const void*  __restrict__ pairs,
    const float* __restrict__ b1,
    const float* __restrict__ W2,
    const float* __restrict__ b2,
    const int*   __restrict__ flag,
    float*       __restrict__ out)
{
  const int tid = threadIdx.x;
  const int ln  = tid & 15;                       // lane within 16-lane subgroup
  const int e   = blockIdx.x * 16 + (tid >> 4);   // one edge per subgroup
  const int is64 = *flag;

  long long u, v;
  if (is64) {
    const long long* q = (const long long*)pairs;
    u = q[2 * e]; v = q[2 * e + 1];
  } else {
    const int* q = (const int*)pairs;
    u = q[2 * e]; v = q[2 * e + 1];
  }

  const float4* P = (const float4*)(R + (size_t)u * 256) + ln * 2;
  const float4* Q = (const float4*)(R + (size_t)v * 256 + 128) + ln * 2;
  float4 p0 = P[0], p1 = P[1];
  float4 q0 = Q[0], q1 = Q[1];
  float4 c0 = ((const float4*)b1)[ln * 2], c1 = ((const float4*)b1)[ln * 2 + 1];
  float4 w0 = ((const float4*)W2)[ln * 2], w1 = ((const float4*)W2)[ln * 2 + 1];

  float s = 0.f;
  s = fmaf(fmaxf(p0.x + q0.x + c0.x, 0.f), w0.x, s);
  s = fmaf(fmaxf(p0.y + q0.y + c0.y, 0.f), w0.y, s);
  s = fmaf(fmaxf(p0.z + q0.z + c0.z, 0.f), w0.z, s);
  s = fmaf(fmaxf(p0.w + q0.w + c0.w, 0.f), w0.w, s);
  s = fmaf(fmaxf(p1.x + q1.x + c1.x, 0.f), w1.x, s);
  s = fmaf(fmaxf(p1.y + q1.y + c1.y, 0.f), w1.y, s);
  s = fmaf(fmaxf(p1.z + q1.z + c1.z, 0.f), w1.z, s);
  s = fmaf(fmaxf(p1.w + q1.w + c1.w, 0.f), w1.w, s);

  s += __shfl_xor(s, 1);
  s += __shfl_xor(s, 2);
  s += __shfl_xor(s, 4);
  s += __shfl_xor(s, 8);

  if (ln == 0) out[e] = s + b2[0];
}

// ---------- FALLBACK: round-1 fused kernel (used if ws too small) ----------
__global__ __launch_bounds__(256) void edge_mlp(
    const float* __restrict__ z,
    const void*  __restrict__ pairs,
    const float* __restrict__ W1,
    const float* __restrict__ b1,
    const float* __restrict__ W2,
    const float* __restrict__ b2,
    const int*   __restrict__ flag,
    float*       __restrict__ out)
{
  __shared__ __align__(16) float As[KT][BP];
  __shared__ __align__(16) float Bs[KT][HIDDEN];

  const int tid = threadIdx.x;
  const int p0  = blockIdx.x * BP;
  const int is64 = *flag;

  const int sp   = tid >> 1;
  const int half = tid & 1;
  const int bk   = tid >> 3;
  const int bc   = (tid & 7) * 16;

  int uu = 0, vv = 0;
  {
    int gp = p0 + sp;
    if (gp < NPAIRS) {
      if (is64) {
        const long long* q = (const long long*)pairs;
        uu = (int)q[2 * gp];
        vv = (int)q[2 * gp + 1];
      } else {
        const int* q = (const int*)pairs;
        uu = q[2 * gp];
        vv = q[2 * gp + 1];
      }
    }
  }

  const int wave  = tid >> 6;
  const int lane  = tid & 63;
  const int pg    = lane >> 3;
  const int cg    = lane & 7;
  const int pbase = (wave >> 1) * 64 + pg * 8;
  const int cbase = (wave & 1)  * 64 + cg * 8;

  float acc[8][8];
  #pragma unroll
  for (int i = 0; i < 8; ++i)
    #pragma unroll
    for (int j = 0; j < 8; ++j) acc[i][j] = 0.f;

  for (int kt = 0; kt < 8; ++kt) {
    {
      const int node = (kt < 4) ? uu : vv;
      const int koff = (kt & 3) * 32 + half * 16;
      const float4* src = (const float4*)(z + (size_t)node * HIDDEN + koff);
      #pragma unroll
      for (int i = 0; i < 4; ++i) {
        float4 v4 = src[i];
        int tk = half * 16 + 4 * i;
        As[tk + 0][sp] = v4.x;
        As[tk + 1][sp] = v4.y;
        As[tk + 2][sp] = v4.z;
        As[tk + 3][sp] = v4.w;
      }
    }
    {
      const float4* src = (const float4*)(W1 + (size_t)(kt * KT + bk) * HIDDEN + bc);
      float4* dst = (float4*)&Bs[bk][bc];
      #pragma unroll
      for (int i = 0; i < 4; ++i) dst[i] = src[i];
    }
    __syncthreads();

    #pragma unroll 8
    for (int k = 0; k < KT; ++k) {
      float4 a0  = *(const float4*)&As[k][pbase];
      float4 a1  = *(const float4*)&As[k][pbase + 4];
      float4 bb0 = *(const float4*)&Bs[k][cbase];
      float4 bb1 = *(const float4*)&Bs[k][cbase + 4];
      float av[8] = {a0.x, a0.y, a0.z, a0.w, a1.x, a1.y, a1.z, a1.w};
      float bv[8] = {bb0.x, bb0.y, bb0.z, bb0.w, bb1.x, bb1.y, bb1.z, bb1.w};
      #pragma unroll
      for (int i = 0; i < 8; ++i)
        #pragma unroll
        for (int j = 0; j < 8; ++j)
          acc[i][j] = fmaf(av[i], bv[j], acc[i][j]);
    }
    __syncthreads();
  }

  float b1v[8], w2v[8];
  #pragma unroll
  for (int j = 0; j < 8; ++j) {
    b1v[j] = b1[cbase + j];
    w2v[j] = W2[cbase + j];
  }
  float psum[8];
  #pragma unroll
  for (int i = 0; i < 8; ++i) {
    float s = 0.f;
    #pragma unroll
    for (int j = 0; j < 8; ++j) {
      float h = fmaxf(acc[i][j] + b1v[j], 0.f);
      s = fmaf(h, w2v[j], s);
    }
    psum[i] = s;
  }

  float* red = &As[0][0];
  const int cidx = (wave & 1) * 8 + cg;
  #pragma unroll
  for (int i = 0; i < 8; ++i) red[(pbase + i) * 16 + cidx] = psum[i];
  __syncthreads();

  if (tid < BP) {
    float s = b2[0];
    #pragma unroll
    for (int j = 0; j < 16; ++j) s += red[tid * 16 + j];
    int gp = p0 + tid;
    if (gp < NPAIRS) out[gp] = s;
  }
}

extern "C" void kernel_launch(void* const* d_in, const int* in_sizes, int n_in,
                              void* d_out, int out_size, void* d_ws, size_t ws_size,
                              hipStream_t stream) {
  const float* z     = (const float*)d_in[0];
  const void*  pairs =               d_in[1];
  const float* W1    = (const float*)d_in[2];
  const float* b1    = (const float*)d_in[3];
  const float* W2    = (const float*)d_in[4];
  const float* b2    = (const float*)d_in[5];
  float* out = (float*)d_out;

  const size_t R_BYTES = (size_t)NUM_NODES * 256 * sizeof(float);  // 102.4 MB

  if (ws_size >= R_BYTES + 256) {
    float* R   = (float*)d_ws;
    int*  flag = (int*)((char*)d_ws + R_BYTES);
    detect_idx64<<<1, 64, 0, stream>>>((const unsigned int*)pairs, flag);
    dim3 grid1((NUM_NODES + 127) / 128, 2);
    node_precompute<<<grid1, 256, 0, stream>>>(z, W1, R);
    edge_pass<<<NPAIRS / 16, 256, 0, stream>>>(R, pairs, b1, W2, b2, flag, out);
  } else {
    int* flag = (int*)d_ws;
    detect_idx64<<<1, 64, 0, stream>>>((const unsigned int*)pairs, flag);
    const int grid = (NPAIRS + BP - 1) / BP;
    edge_mlp<<<grid, 256, 0, stream>>>(z, pairs, W1, b1, W2, b2, flag, out);
  }
}

// Round 8
// 248.722 us; speedup vs baseline: 3.1014x; 1.2357x over previous
//
#include <hip/hip_runtime.h>
#include <hip/hip_fp16.h>

#define NUM_NODES 100000
#define HIDDEN 128
#define NPAIRS 1000000

constexpr int BP = 128;   // pairs per block (fallback kernel)
constexpr int KT = 32;    // k-tile depth

// ---------- idx dtype detection (int64 vs int32), wave-parallel ----------
__global__ void detect_idx64(const unsigned int* __restrict__ raw, int* __restrict__ flag) {
  // 64 threads check dwords 1,3,...,127 (high words of first 64 int64s).
  unsigned v = raw[2 * threadIdx.x + 1];
  unsigned long long b = __ballot(v == 0u);
  if (threadIdx.x == 0) *flag = (b == ~0ull) ? 1 : 0;
}

static __device__ __forceinline__ __half2 pack2(float a, float b) {
  __half2 h;
  h.x = __float2half_rn(a);
  h.y = __float2half_rn(b);
  return h;
}

// Decode one float's bit pattern as 2 halves -> 2 floats. Single-variable cast: well-defined.
static __device__ __forceinline__ float2 h2tof2(float bits) {
  __half2 h = __builtin_bit_cast(__half2, bits);
  return make_float2(__low2float(h), __high2float(h));
}

// ---------- kernel 1: Rh[n, 0:128]=z[n]@W1[:128], Rh[n,128:256]=z[n]@W1[128:] (fp16 out) ----------
__global__ __launch_bounds__(256) void node_precompute(
    const float* __restrict__ z,
    const float* __restrict__ W1,
    __half*      __restrict__ Rh)
{
  __shared__ __align__(16) float As[KT][128];
  __shared__ __align__(16) float Bs[KT][128];

  const int tid = threadIdx.x;
  const int m0  = blockIdx.x * 128;
  const int hsel = blockIdx.y;          // 0 -> P (W1 rows 0..127), 1 -> Q (rows 128..255)

  const int sp   = tid >> 1;            // z row staged
  const int half = tid & 1;
  const int bk   = tid >> 3;            // W1 row within k-tile
  const int bc   = (tid & 7) * 16;

  const int zrow = (m0 + sp < NUM_NODES) ? (m0 + sp) : 0;

  const int wave  = tid >> 6;
  const int lane  = tid & 63;
  const int pg    = lane >> 3;
  const int cg    = lane & 7;
  const int pbase = (wave >> 1) * 64 + pg * 8;
  const int cbase = (wave & 1)  * 64 + cg * 8;

  float acc[8][8];
  #pragma unroll
  for (int i = 0; i < 8; ++i)
    #pragma unroll
    for (int j = 0; j < 8; ++j) acc[i][j] = 0.f;

  for (int kt = 0; kt < 4; ++kt) {
    {
      const float4* src = (const float4*)(z + (size_t)zrow * HIDDEN + kt * KT + half * 16);
      #pragma unroll
      for (int i = 0; i < 4; ++i) {
        float4 v4 = src[i];
        int tk = half * 16 + 4 * i;
        As[tk + 0][sp] = v4.x;
        As[tk + 1][sp] = v4.y;
        As[tk + 2][sp] = v4.z;
        As[tk + 3][sp] = v4.w;
      }
    }
    {
      const float4* src = (const float4*)(W1 + (size_t)(hsel * 128 + kt * KT + bk) * HIDDEN + bc);
      float4* dst = (float4*)&Bs[bk][bc];
      #pragma unroll
      for (int i = 0; i < 4; ++i) dst[i] = src[i];
    }
    __syncthreads();

    #pragma unroll 8
    for (int k = 0; k < KT; ++k) {
      float4 a0  = *(const float4*)&As[k][pbase];
      float4 a1  = *(const float4*)&As[k][pbase + 4];
      float4 bb0 = *(const float4*)&Bs[k][cbase];
      float4 bb1 = *(const float4*)&Bs[k][cbase + 4];
      float av[8] = {a0.x, a0.y, a0.z, a0.w, a1.x, a1.y, a1.z, a1.w};
      float bv[8] = {bb0.x, bb0.y, bb0.z, bb0.w, bb1.x, bb1.y, bb1.z, bb1.w};
      #pragma unroll
      for (int i = 0; i < 8; ++i)
        #pragma unroll
        for (int j = 0; j < 8; ++j)
          acc[i][j] = fmaf(av[i], bv[j], acc[i][j]);
    }
    __syncthreads();
  }

  // epilogue: pack 8 cols to fp16 (16B) and store
  #pragma unroll
  for (int i = 0; i < 8; ++i) {
    int r = m0 + pbase + i;
    if (r < NUM_NODES) {
      float4 packed;
      __half2* hp = (__half2*)&packed;   // within one variable: OK
      hp[0] = pack2(acc[i][0], acc[i][1]);
      hp[1] = pack2(acc[i][2], acc[i][3]);
      hp[2] = pack2(acc[i][4], acc[i][5]);
      hp[3] = pack2(acc[i][6], acc[i][7]);
      *(float4*)(Rh + (size_t)r * 256 + hsel * 128 + cbase) = packed;
    }
  }
}

// ---------- kernel 2: per-edge fused relu + dot (fp16 table, 8-lane subgroups) ----------
__global__ __launch_bounds__(256) void edge_pass(
    const __half* __restrict__ Rh,
    const void*   __restrict__ pairs,
    const float*  __restrict__ b1,
    const float*  __restrict__ W2,
    const float*  __restrict__ b2,
    const int*    __restrict__ flag,
    float*        __restrict__ out)
{
  const int tid = threadIdx.x;
  const int ln  = tid & 7;                        // lane within 8-lane subgroup
  const int e   = blockIdx.x * 32 + (tid >> 3);   // one edge per subgroup
  const int is64 = *flag;

  long long u, v;
  if (is64) {
    const long long* q = (const long long*)pairs;
    u = q[2 * e]; v = q[2 * e + 1];
  } else {
    const int* q = (const int*)pairs;
    u = q[2 * e]; v = q[2 * e + 1];
  }

  // lane ln covers cols [ln*16, ln*16+16): two float4 loads = 16 halves
  const float4* Pu = (const float4*)(Rh + (size_t)u * 256 + ln * 16);
  const float4* Qv = (const float4*)(Rh + (size_t)v * 256 + 128 + ln * 16);
  float4 pu0 = Pu[0], pu1 = Pu[1];
  float4 qv0 = Qv[0], qv1 = Qv[1];

  const float4* b1p = (const float4*)(b1 + ln * 16);
  const float4* w2p = (const float4*)(W2 + ln * 16);
  float4 c0 = b1p[0], c1 = b1p[1], c2 = b1p[2], c3 = b1p[3];
  float4 w0 = w2p[0], w1 = w2p[1], w2_ = w2p[2], w3 = w2p[3];

  float s = 0.f;
  {
    float2 p, q;
    p = h2tof2(pu0.x); q = h2tof2(qv0.x);
    s = fmaf(fmaxf(p.x + q.x + c0.x, 0.f), w0.x, s);
    s = fmaf(fmaxf(p.y + q.y + c0.y, 0.f), w0.y, s);
    p = h2tof2(pu0.y); q = h2tof2(qv0.y);
    s = fmaf(fmaxf(p.x + q.x + c0.z, 0.f), w0.z, s);
    s = fmaf(fmaxf(p.y + q.y + c0.w, 0.f), w0.w, s);
    p = h2tof2(pu0.z); q = h2tof2(qv0.z);
    s = fmaf(fmaxf(p.x + q.x + c1.x, 0.f), w1.x, s);
    s = fmaf(fmaxf(p.y + q.y + c1.y, 0.f), w1.y, s);
    p = h2tof2(pu0.w); q = h2tof2(qv0.w);
    s = fmaf(fmaxf(p.x + q.x + c1.z, 0.f), w1.z, s);
    s = fmaf(fmaxf(p.y + q.y + c1.w, 0.f), w1.w, s);
    p = h2tof2(pu1.x); q = h2tof2(qv1.x);
    s = fmaf(fmaxf(p.x + q.x + c2.x, 0.f), w2_.x, s);
    s = fmaf(fmaxf(p.y + q.y + c2.y, 0.f), w2_.y, s);
    p = h2tof2(pu1.y); q = h2tof2(qv1.y);
    s = fmaf(fmaxf(p.x + q.x + c2.z, 0.f), w2_.z, s);
    s = fmaf(fmaxf(p.y + q.y + c2.w, 0.f), w2_.w, s);
    p = h2tof2(pu1.z); q = h2tof2(qv1.z);
    s = fmaf(fmaxf(p.x + q.x + c3.x, 0.f), w3.x, s);
    s = fmaf(fmaxf(p.y + q.y + c3.y, 0.f), w3.y, s);
    p = h2tof2(pu1.w); q = h2tof2(qv1.w);
    s = fmaf(fmaxf(p.x + q.x + c3.z, 0.f), w3.z, s);
    s = fmaf(fmaxf(p.y + q.y + c3.w, 0.f), w3.w, s);
  }

  s += __shfl_xor(s, 1);
  s += __shfl_xor(s, 2);
  s += __shfl_xor(s, 4);

  if (ln == 0) out[e] = s + b2[0];
}

// ---------- FALLBACK: round-1 fused kernel (used if ws too small) ----------
__global__ __launch_bounds__(256) void edge_mlp(
    const float* __restrict__ z,
    const void*  __restrict__ pairs,
    const float* __restrict__ W1,
    const float* __restrict__ b1,
    const float* __restrict__ W2,
    const float* __restrict__ b2,
    const int*   __restrict__ flag,
    float*       __restrict__ out)
{
  __shared__ __align__(16) float As[KT][BP];
  __shared__ __align__(16) float Bs[KT][HIDDEN];

  const int tid = threadIdx.x;
  const int p0  = blockIdx.x * BP;
  const int is64 = *flag;

  const int sp   = tid >> 1;
  const int half = tid & 1;
  const int bk   = tid >> 3;
  const int bc   = (tid & 7) * 16;

  int uu = 0, vv = 0;
  {
    int gp = p0 + sp;
    if (gp < NPAIRS) {
      if (is64) {
        const long long* q = (const long long*)pairs;
        uu = (int)q[2 * gp];
        vv = (int)q[2 * gp + 1];
      } else {
        const int* q = (const int*)pairs;
        uu = q[2 * gp];
        vv = q[2 * gp + 1];
      }
    }
  }

  const int wave  = tid >> 6;
  const int lane  = tid & 63;
  const int pg    = lane >> 3;
  const int cg    = lane & 7;
  const int pbase = (wave >> 1) * 64 + pg * 8;
  const int cbase = (wave & 1)  * 64 + cg * 8;

  float acc[8][8];
  #pragma unroll
  for (int i = 0; i < 8; ++i)
    #pragma unroll
    for (int j = 0; j < 8; ++j) acc[i][j] = 0.f;

  for (int kt = 0; kt < 8; ++kt) {
    {
      const int node = (kt < 4) ? uu : vv;
      const int koff = (kt & 3) * 32 + half * 16;
      const float4* src = (const float4*)(z + (size_t)node * HIDDEN + koff);
      #pragma unroll
      for (int i = 0; i < 4; ++i) {
        float4 v4 = src[i];
        int tk = half * 16 + 4 * i;
        As[tk + 0][sp] = v4.x;
        As[tk + 1][sp] = v4.y;
        As[tk + 2][sp] = v4.z;
        As[tk + 3][sp] = v4.w;
      }
    }
    {
      const float4* src = (const float4*)(W1 + (size_t)(kt * KT + bk) * HIDDEN + bc);
      float4* dst = (float4*)&Bs[bk][bc];
      #pragma unroll
      for (int i = 0; i < 4; ++i) dst[i] = src[i];
    }
    __syncthreads();

    #pragma unroll 8
    for (int k = 0; k < KT; ++k) {
      float4 a0  = *(const float4*)&As[k][pbase];
      float4 a1  = *(const float4*)&As[k][pbase + 4];
      float4 bb0 = *(const float4*)&Bs[k][cbase];
      float4 bb1 = *(const float4*)&Bs[k][cbase + 4];
      float av[8] = {a0.x, a0.y, a0.z, a0.w, a1.x, a1.y, a1.z, a1.w};
      float bv[8] = {bb0.x, bb0.y, bb0.z, bb0.w, bb1.x, bb1.y, bb1.z, bb1.w};
      #pragma unroll
      for (int i = 0; i < 8; ++i)
        #pragma unroll
        for (int j = 0; j < 8; ++j)
          acc[i][j] = fmaf(av[i], bv[j], acc[i][j]);
    }
    __syncthreads();
  }

  float b1v[8], w2v[8];
  #pragma unroll
  for (int j = 0; j < 8; ++j) {
    b1v[j] = b1[cbase + j];
    w2v[j] = W2[cbase + j];
  }
  float psum[8];
  #pragma unroll
  for (int i = 0; i < 8; ++i) {
    float s = 0.f;
    #pragma unroll
    for (int j = 0; j < 8; ++j) {
      float h = fmaxf(acc[i][j] + b1v[j], 0.f);
      s = fmaf(h, w2v[j], s);
    }
    psum[i] = s;
  }

  float* red = &As[0][0];
  const int cidx = (wave & 1) * 8 + cg;
  #pragma unroll
  for (int i = 0; i < 8; ++i) red[(pbase + i) * 16 + cidx] = psum[i];
  __syncthreads();

  if (tid < BP) {
    float s = b2[0];
    #pragma unroll
    for (int j = 0; j < 16; ++j) s += red[tid * 16 + j];
    int gp = p0 + tid;
    if (gp < NPAIRS) out[gp] = s;
  }
}

extern "C" void kernel_launch(void* const* d_in, const int* in_sizes, int n_in,
                              void* d_out, int out_size, void* d_ws, size_t ws_size,
                              hipStream_t stream) {
  const float* z     = (const float*)d_in[0];
  const void*  pairs =               d_in[1];
  const float* W1    = (const float*)d_in[2];
  const float* b1    = (const float*)d_in[3];
  const float* W2    = (const float*)d_in[4];
  const float* b2    = (const float*)d_in[5];
  float* out = (float*)d_out;

  const size_t R_BYTES = (size_t)NUM_NODES * 256 * sizeof(__half);  // 51.2 MB

  if (ws_size >= R_BYTES + 256) {
    __half* Rh = (__half*)d_ws;
    int*  flag = (int*)((char*)d_ws + R_BYTES);
    detect_idx64<<<1, 64, 0, stream>>>((const unsigned int*)pairs, flag);
    dim3 grid1((NUM_NODES + 127) / 128, 2);
    node_precompute<<<grid1, 256, 0, stream>>>(z, W1, Rh);
    edge_pass<<<NPAIRS / 32, 256, 0, stream>>>(Rh, pairs, b1, W2, b2, flag, out);
  } else {
    int* flag = (int*)d_ws;
    detect_idx64<<<1, 64, 0, stream>>>((const unsigned int*)pairs, flag);
    const int grid = (NPAIRS + BP - 1) / BP;
    edge_mlp<<<grid, 256, 0, stream>>>(z, pairs, W1, b1, W2, b2, flag, out);
  }
}

// Round 9
// 203.808 us; speedup vs baseline: 3.7849x; 1.2204x over previous
//
#include <hip/hip_runtime.h>
#include <hip/hip_fp16.h>

#define NUM_NODES 100000
#define HIDDEN 128
#define NPAIRS 1000000

constexpr int BP = 128;   // pairs per block (fallback kernel)
constexpr int KT = 32;    // k-tile depth (fallback kernel)
constexpr int PAD = 136;  // f16 row stride: 272 B -> bank stride 4, 2-way (free)

typedef _Float16 f16;
typedef f16 f16x8 __attribute__((ext_vector_type(8)));
typedef float f32x4 __attribute__((ext_vector_type(4)));

// ---------- idx dtype detection (int64 vs int32), wave-parallel ----------
__global__ void detect_idx64(const unsigned int* __restrict__ raw, int* __restrict__ flag) {
  unsigned v = raw[2 * threadIdx.x + 1];
  unsigned long long b = __ballot(v == 0u);
  if (threadIdx.x == 0) *flag = (b == ~0ull) ? 1 : 0;
}

// Decode one float's bit pattern as 2 halves -> 2 floats. Single-variable cast: well-defined.
static __device__ __forceinline__ float2 h2tof2(float bits) {
  __half2 h = __builtin_bit_cast(__half2, bits);
  return make_float2(__low2float(h), __high2float(h));
}

// ---------- kernel 1 (MFMA): Rh[n, hsel*128 + j] = sum_k z[n,k] * W1[hsel*128 + k, j] ----------
__global__ __launch_bounds__(256) void node_precompute_mfma(
    const float* __restrict__ z,
    const float* __restrict__ W1,
    __half*      __restrict__ Rh)
{
  __shared__ __align__(16) f16 As[128 * PAD];  // A: [M=128][K=128] row-major, padded
  __shared__ __align__(16) f16 Bt[128 * PAD];  // B^T: [N=128][K=128], padded

  const int tid  = threadIdx.x;
  const int m0   = blockIdx.x * 128;
  const int hsel = blockIdx.y;   // 0 -> P (W1 rows 0..127), 1 -> Q (W1 rows 128..255)

  // ---- stage A: z rows fp32 -> f16
  {
    const int row  = tid >> 1;
    const int half = tid & 1;
    int zr = m0 + row; if (zr >= NUM_NODES) zr = 0;
    const float4* src = (const float4*)(z + (size_t)zr * HIDDEN + half * 64);
    f16* dst = As + row * PAD + half * 64;
    #pragma unroll
    for (int i = 0; i < 16; i += 2) {
      float4 a = src[i];
      float4 b = src[i + 1];
      f16x8 h;
      h[0] = (f16)a.x; h[1] = (f16)a.y; h[2] = (f16)a.z; h[3] = (f16)a.w;
      h[4] = (f16)b.x; h[5] = (f16)b.y; h[6] = (f16)b.z; h[7] = (f16)b.w;
      *(f16x8*)(dst + i * 4) = h;
    }
  }
  // ---- stage Bt (transposed): Bt[col][k] = W1[hsel*128 + k][col]
  {
    const int k    = tid >> 1;
    const int half = tid & 1;
    const float4* src = (const float4*)(W1 + (size_t)(hsel * 128 + k) * HIDDEN + half * 64);
    #pragma unroll
    for (int i = 0; i < 16; ++i) {
      float4 a = src[i];
      int c = half * 64 + i * 4;
      Bt[(c + 0) * PAD + k] = (f16)a.x;
      Bt[(c + 1) * PAD + k] = (f16)a.y;
      Bt[(c + 2) * PAD + k] = (f16)a.z;
      Bt[(c + 3) * PAD + k] = (f16)a.w;
    }
  }
  __syncthreads();

  const int wave  = tid >> 6;
  const int lane  = tid & 63;
  const int lrow  = lane & 15;   // A row / B col / D col
  const int kgrp  = lane >> 4;   // k-chunk (input frags) / row-group (D)
  const int rbase = wave * 32;   // this wave owns rows [rbase, rbase+32)

  // A fragments: af[rt][k] = A[rbase+rt*16+lrow][k*32 + kgrp*8 .. +8]
  f16x8 af[2][4];
  #pragma unroll
  for (int rt = 0; rt < 2; ++rt)
    #pragma unroll
    for (int k = 0; k < 4; ++k)
      af[rt][k] = *(const f16x8*)(As + (rbase + rt * 16 + lrow) * PAD + k * 32 + kgrp * 8);

  f32x4 acc[2][8];
  #pragma unroll
  for (int rt = 0; rt < 2; ++rt)
    #pragma unroll
    for (int ct = 0; ct < 8; ++ct)
      acc[rt][ct] = (f32x4){0.f, 0.f, 0.f, 0.f};

  #pragma unroll
  for (int ct = 0; ct < 8; ++ct) {
    f16x8 bf[4];
    #pragma unroll
    for (int k = 0; k < 4; ++k)
      bf[k] = *(const f16x8*)(Bt + (ct * 16 + lrow) * PAD + k * 32 + kgrp * 8);
    #pragma unroll
    for (int rt = 0; rt < 2; ++rt)
      #pragma unroll
      for (int k = 0; k < 4; ++k)
        acc[rt][ct] = __builtin_amdgcn_mfma_f32_16x16x32_f16(af[rt][k], bf[k], acc[rt][ct], 0, 0, 0);
  }

  __syncthreads();
  // D -> LDS (f16), m89-verified mapping: col = lane&15, row = (lane>>4)*4 + reg
  #pragma unroll
  for (int rt = 0; rt < 2; ++rt)
    #pragma unroll
    for (int ct = 0; ct < 8; ++ct)
      #pragma unroll
      for (int r = 0; r < 4; ++r) {
        int row = rbase + rt * 16 + kgrp * 4 + r;
        int col = ct * 16 + lrow;
        As[row * PAD + col] = (f16)acc[rt][ct][r];
      }
  __syncthreads();

  // coalesced copy-out
  {
    const int row  = tid >> 1;
    const int half = tid & 1;
    int gr = m0 + row;
    if (gr < NUM_NODES) {
      const f16* srcr = As + row * PAD + half * 64;
      float4* dst = (float4*)((f16*)Rh + (size_t)gr * 256 + hsel * 128 + half * 64);
      #pragma unroll
      for (int i = 0; i < 8; ++i)
        dst[i] = *(const float4*)(srcr + i * 8);
    }
  }
}

// ---------- kernel 2: per-edge fused relu + dot (fp16 table, 8-lane subgroups) ----------
__global__ __launch_bounds__(256) void edge_pass(
    const __half* __restrict__ Rh,
    const void*   __restrict__ pairs,
    const float*  __restrict__ b1,
    const float*  __restrict__ W2,
    const float*  __restrict__ b2,
    const int*    __restrict__ flag,
    float*        __restrict__ out)
{
  const int tid = threadIdx.x;
  const int ln  = tid & 7;                        // lane within 8-lane subgroup
  const int e   = blockIdx.x * 32 + (tid >> 3);   // one edge per subgroup
  const int is64 = *flag;

  long long u, v;
  if (is64) {
    const long long* q = (const long long*)pairs;
    u = q[2 * e]; v = q[2 * e + 1];
  } else {
    const int* q = (const int*)pairs;
    u = q[2 * e]; v = q[2 * e + 1];
  }

  const float4* Pu = (const float4*)(Rh + (size_t)u * 256 + ln * 16);
  const float4* Qv = (const float4*)(Rh + (size_t)v * 256 + 128 + ln * 16);
  float4 pu0 = Pu[0], pu1 = Pu[1];
  float4 qv0 = Qv[0], qv1 = Qv[1];

  const float4* b1p = (const float4*)(b1 + ln * 16);
  const float4* w2p = (const float4*)(W2 + ln * 16);
  float4 c0 = b1p[0], c1 = b1p[1], c2 = b1p[2], c3 = b1p[3];
  float4 w0 = w2p[0], w1 = w2p[1], w2_ = w2p[2], w3 = w2p[3];

  float s = 0.f;
  {
    float2 p, q;
    p = h2tof2(pu0.x); q = h2tof2(qv0.x);
    s = fmaf(fmaxf(p.x + q.x + c0.x, 0.f), w0.x, s);
    s = fmaf(fmaxf(p.y + q.y + c0.y, 0.f), w0.y, s);
    p = h2tof2(pu0.y); q = h2tof2(qv0.y);
    s = fmaf(fmaxf(p.x + q.x + c0.z, 0.f), w0.z, s);
    s = fmaf(fmaxf(p.y + q.y + c0.w, 0.f), w0.w, s);
    p = h2tof2(pu0.z); q = h2tof2(qv0.z);
    s = fmaf(fmaxf(p.x + q.x + c1.x, 0.f), w1.x, s);
    s = fmaf(fmaxf(p.y + q.y + c1.y, 0.f), w1.y, s);
    p = h2tof2(pu0.w); q = h2tof2(qv0.w);
    s = fmaf(fmaxf(p.x + q.x + c1.z, 0.f), w1.z, s);
    s = fmaf(fmaxf(p.y + q.y + c1.w, 0.f), w1.w, s);
    p = h2tof2(pu1.x); q = h2tof2(qv1.x);
    s = fmaf(fmaxf(p.x + q.x + c2.x, 0.f), w2_.x, s);
    s = fmaf(fmaxf(p.y + q.y + c2.y, 0.f), w2_.y, s);
    p = h2tof2(pu1.y); q = h2tof2(qv1.y);
    s = fmaf(fmaxf(p.x + q.x + c2.z, 0.f), w2_.z, s);
    s = fmaf(fmaxf(p.y + q.y + c2.w, 0.f), w2_.w, s);
    p = h2tof2(pu1.z); q = h2tof2(qv1.z);
    s = fmaf(fmaxf(p.x + q.x + c3.x, 0.f), w3.x, s);
    s = fmaf(fmaxf(p.y + q.y + c3.y, 0.f), w3.y, s);
    p = h2tof2(pu1.w); q = h2tof2(qv1.w);
    s = fmaf(fmaxf(p.x + q.x + c3.z, 0.f), w3.z, s);
    s = fmaf(fmaxf(p.y + q.y + c3.w, 0.f), w3.w, s);
  }

  s += __shfl_xor(s, 1);
  s += __shfl_xor(s, 2);
  s += __shfl_xor(s, 4);

  if (ln == 0) out[e] = s + b2[0];
}

// ---------- FALLBACK: round-1 fused kernel (used if ws too small) ----------
__global__ __launch_bounds__(256) void edge_mlp(
    const float* __restrict__ z,
    const void*  __restrict__ pairs,
    const float* __restrict__ W1,
    const float* __restrict__ b1,
    const float* __restrict__ W2,
    const float* __restrict__ b2,
    const int*   __restrict__ flag,
    float*       __restrict__ out)
{
  __shared__ __align__(16) float Asf[KT][BP];
  __shared__ __align__(16) float Bsf[KT][HIDDEN];

  const int tid = threadIdx.x;
  const int p0  = blockIdx.x * BP;
  const int is64 = *flag;

  const int sp   = tid >> 1;
  const int half = tid & 1;
  const int bk   = tid >> 3;
  const int bc   = (tid & 7) * 16;

  int uu = 0, vv = 0;
  {
    int gp = p0 + sp;
    if (gp < NPAIRS) {
      if (is64) {
        const long long* q = (const long long*)pairs;
        uu = (int)q[2 * gp];
        vv = (int)q[2 * gp + 1];
      } else {
        const int* q = (const int*)pairs;
        uu = q[2 * gp];
        vv = q[2 * gp + 1];
      }
    }
  }

  const int wave  = tid >> 6;
  const int lane  = tid & 63;
  const int pg    = lane >> 3;
  const int cg    = lane & 7;
  const int pbase = (wave >> 1) * 64 + pg * 8;
  const int cbase = (wave & 1)  * 64 + cg * 8;

  float acc[8][8];
  #pragma unroll
  for (int i = 0; i < 8; ++i)
    #pragma unroll
    for (int j = 0; j < 8; ++j) acc[i][j] = 0.f;

  for (int kt = 0; kt < 8; ++kt) {
    {
      const int node = (kt < 4) ? uu : vv;
      const int koff = (kt & 3) * 32 + half * 16;
      const float4* src = (const float4*)(z + (size_t)node * HIDDEN + koff);
      #pragma unroll
      for (int i = 0; i < 4; ++i) {
        float4 v4 = src[i];
        int tk = half * 16 + 4 * i;
        Asf[tk + 0][sp] = v4.x;
        Asf[tk + 1][sp] = v4.y;
        Asf[tk + 2][sp] = v4.z;
        Asf[tk + 3][sp] = v4.w;
      }
    }
    {
      const float4* src = (const float4*)(W1 + (size_t)(kt * KT + bk) * HIDDEN + bc);
      float4* dst = (float4*)&Bsf[bk][bc];
      #pragma unroll
      for (int i = 0; i < 4; ++i) dst[i] = src[i];
    }
    __syncthreads();

    #pragma unroll 8
    for (int k = 0; k < KT; ++k) {
      float4 a0  = *(const float4*)&Asf[k][pbase];
      float4 a1  = *(const float4*)&Asf[k][pbase + 4];
      float4 bb0 = *(const float4*)&Bsf[k][cbase];
      float4 bb1 = *(const float4*)&Bsf[k][cbase + 4];
      float av[8] = {a0.x, a0.y, a0.z, a0.w, a1.x, a1.y, a1.z, a1.w};
      float bv[8] = {bb0.x, bb0.y, bb0.z, bb0.w, bb1.x, bb1.y, bb1.z, bb1.w};
      #pragma unroll
      for (int i = 0; i < 8; ++i)
        #pragma unroll
        for (int j = 0; j < 8; ++j)
          acc[i][j] = fmaf(av[i], bv[j], acc[i][j]);
    }
    __syncthreads();
  }

  float b1v[8], w2v[8];
  #pragma unroll
  for (int j = 0; j < 8; ++j) {
    b1v[j] = b1[cbase + j];
    w2v[j] = W2[cbase + j];
  }
  float psum[8];
  #pragma unroll
  for (int i = 0; i < 8; ++i) {
    float s = 0.f;
    #pragma unroll
    for (int j = 0; j < 8; ++j) {
      float h = fmaxf(acc[i][j] + b1v[j], 0.f);
      s = fmaf(h, w2v[j], s);
    }
    psum[i] = s;
  }

  float* red = &Asf[0][0];
  const int cidx = (wave & 1) * 8 + cg;
  #pragma unroll
  for (int i = 0; i < 8; ++i) red[(pbase + i) * 16 + cidx] = psum[i];
  __syncthreads();

  if (tid < BP) {
    float s = b2[0];
    #pragma unroll
    for (int j = 0; j < 16; ++j) s += red[tid * 16 + j];
    int gp = p0 + tid;
    if (gp < NPAIRS) out[gp] = s;
  }
}

extern "C" void kernel_launch(void* const* d_in, const int* in_sizes, int n_in,
                              void* d_out, int out_size, void* d_ws, size_t ws_size,
                              hipStream_t stream) {
  const float* z     = (const float*)d_in[0];
  const void*  pairs =               d_in[1];
  const float* W1    = (const float*)d_in[2];
  const float* b1    = (const float*)d_in[3];
  const float* W2    = (const float*)d_in[4];
  const float* b2    = (const float*)d_in[5];
  float* out = (float*)d_out;

  const size_t R_BYTES = (size_t)NUM_NODES * 256 * sizeof(__half);  // 51.2 MB

  if (ws_size >= R_BYTES + 256) {
    __half* Rh = (__half*)d_ws;
    int*  flag = (int*)((char*)d_ws + R_BYTES);
    detect_idx64<<<1, 64, 0, stream>>>((const unsigned int*)pairs, flag);
    dim3 grid1((NUM_NODES + 127) / 128, 2);
    node_precompute_mfma<<<grid1, 256, 0, stream>>>(z, W1, Rh);
    edge_pass<<<NPAIRS / 32, 256, 0, stream>>>(Rh, pairs, b1, W2, b2, flag, out);
  } else {
    int* flag = (int*)d_ws;
    detect_idx64<<<1, 64, 0, stream>>>((const unsigned int*)pairs, flag);
    const int grid = (NPAIRS + BP - 1) / BP;
    edge_mlp<<<grid, 256, 0, stream>>>(z, pairs, W1, b1, W2, b2, flag, out);
  }
}

// Round 12
// 198.441 us; speedup vs baseline: 3.8872x; 1.0270x over previous
//
#include <hip/hip_runtime.h>
#include <hip/hip_fp16.h>

#define NUM_NODES 100000
#define HIDDEN 128
#define NPAIRS 1000000

constexpr int BP = 128;   // pairs per block (fallback kernel)
constexpr int KT = 32;    // k-tile depth (fallback kernel)
constexpr int PAD = 136;  // f16 row stride: 272 B -> 2-way bank aliasing (free, m136)

typedef _Float16 f16;
typedef f16 f16x8 __attribute__((ext_vector_type(8)));
typedef float f32x4 __attribute__((ext_vector_type(4)));

// ---------- idx dtype detection (int64 vs int32), wave-parallel ----------
__global__ void detect_idx64(const unsigned int* __restrict__ raw, int* __restrict__ flag) {
  unsigned v = raw[2 * threadIdx.x + 1];
  unsigned long long b = __ballot(v == 0u);
  if (threadIdx.x == 0) *flag = (b == ~0ull) ? 1 : 0;
}

// Decode one float's bit pattern as 2 halves -> 2 floats. Single-variable cast: well-defined.
static __device__ __forceinline__ float2 h2tof2(float bits) {
  __half2 h = __builtin_bit_cast(__half2, bits);
  return make_float2(__low2float(h), __high2float(h));
}

// ---------- kernel 0: one-time W1 transpose to f16: W1t[h][c][k] = W1[h*128+k][c] ----------
__global__ __launch_bounds__(256) void transpose_w1(
    const float* __restrict__ W1,   // [256][128] fp32
    f16*         __restrict__ W1t)  // [2][128][128] f16, K-contiguous
{
  __shared__ float tile[32][33];
  const int kb = blockIdx.x * 32;
  const int cb = blockIdx.y * 32;
  const int h  = blockIdx.z;
  const int tx = threadIdx.x & 31;
  const int ty = threadIdx.x >> 5;   // 0..7
  #pragma unroll
  for (int i = 0; i < 4; ++i) {
    int k = ty + i * 8;
    tile[k][tx] = W1[(size_t)(h * 128 + kb + k) * HIDDEN + cb + tx];
  }
  __syncthreads();
  #pragma unroll
  for (int i = 0; i < 4; ++i) {
    int c = ty + i * 8;
    W1t[(size_t)h * 16384 + (size_t)(cb + c) * 128 + kb + tx] = (f16)tile[tx][c];
  }
}

// ---------- kernel 1 (MFMA): Rh[n, hsel*128 + j] = sum_k z[n,k] * W1[hsel*128 + k, j] ----------
__global__ __launch_bounds__(256) void node_precompute_mfma(
    const float* __restrict__ z,
    const f16*   __restrict__ W1t,   // [2][128][128], K-contiguous (pre-transposed)
    __half*      __restrict__ Rh)
{
  __shared__ __align__(16) f16 As[128 * PAD];  // A: [M=128][K=128] row-major, padded
  __shared__ __align__(16) f16 Bt[128 * PAD];  // B^T: [N=128][K=128], padded

  const int tid  = threadIdx.x;
  const int m0   = blockIdx.x * 128;
  const int hsel = blockIdx.y;   // 0 -> P (W1 rows 0..127), 1 -> Q (W1 rows 128..255)

  // ---- stage A: z rows fp32 -> f16 (each thread: half a row)
  {
    const int row  = tid >> 1;
    const int half = tid & 1;
    int zr = m0 + row; if (zr >= NUM_NODES) zr = 0;
    const float4* src = (const float4*)(z + (size_t)zr * HIDDEN + half * 64);
    f16* dst = As + row * PAD + half * 64;
    #pragma unroll
    for (int i = 0; i < 16; i += 2) {
      float4 a = src[i];
      float4 b = src[i + 1];
      f16x8 h;
      h[0] = (f16)a.x; h[1] = (f16)a.y; h[2] = (f16)a.z; h[3] = (f16)a.w;
      h[4] = (f16)b.x; h[5] = (f16)b.y; h[6] = (f16)b.z; h[7] = (f16)b.w;
      *(f16x8*)(dst + i * 4) = h;
    }
  }
  // ---- stage Bt: straight vectorized copy from pre-transposed W1t (L2-resident, 32 KB)
  {
    const int c    = tid >> 1;
    const int half = tid & 1;
    const f16* src = W1t + (size_t)hsel * 16384 + (size_t)c * 128 + half * 64;
    f16* dst = Bt + c * PAD + half * 64;
    #pragma unroll
    for (int i = 0; i < 8; ++i)
      *(f16x8*)(dst + i * 8) = *(const f16x8*)(src + i * 8);
  }
  __syncthreads();

  const int wave  = tid >> 6;
  const int lane  = tid & 63;
  const int lrow  = lane & 15;   // A row / B col / D col
  const int kgrp  = lane >> 4;   // k-chunk (input frags) / row-group (D)
  const int rbase = wave * 32;   // this wave owns rows [rbase, rbase+32)

  // A fragments: af[rt][k] = A[rbase+rt*16+lrow][k*32 + kgrp*8 .. +8]
  f16x8 af[2][4];
  #pragma unroll
  for (int rt = 0; rt < 2; ++rt)
    #pragma unroll
    for (int k = 0; k < 4; ++k)
      af[rt][k] = *(const f16x8*)(As + (rbase + rt * 16 + lrow) * PAD + k * 32 + kgrp * 8);

  f32x4 acc[2][8];
  #pragma unroll
  for (int rt = 0; rt < 2; ++rt)
    #pragma unroll
    for (int ct = 0; ct < 8; ++ct)
      acc[rt][ct] = (f32x4){0.f, 0.f, 0.f, 0.f};

  #pragma unroll
  for (int ct = 0; ct < 8; ++ct) {
    f16x8 bf[4];
    #pragma unroll
    for (int k = 0; k < 4; ++k)
      bf[k] = *(const f16x8*)(Bt + (ct * 16 + lrow) * PAD + k * 32 + kgrp * 8);
    #pragma unroll
    for (int rt = 0; rt < 2; ++rt)
      #pragma unroll
      for (int k = 0; k < 4; ++k)
        acc[rt][ct] = __builtin_amdgcn_mfma_f32_16x16x32_f16(af[rt][k], bf[k], acc[rt][ct], 0, 0, 0);
  }

  __syncthreads();
  // D -> LDS (f16), m89-verified mapping: col = lane&15, row = (lane>>4)*4 + reg
  #pragma unroll
  for (int rt = 0; rt < 2; ++rt)
    #pragma unroll
    for (int ct = 0; ct < 8; ++ct)
      #pragma unroll
      for (int r = 0; r < 4; ++r) {
        int row = rbase + rt * 16 + kgrp * 4 + r;
        int col = ct * 16 + lrow;
        As[row * PAD + col] = (f16)acc[rt][ct][r];
      }
  __syncthreads();

  // coalesced copy-out
  {
    const int row  = tid >> 1;
    const int half = tid & 1;
    int gr = m0 + row;
    if (gr < NUM_NODES) {
      const f16* srcr = As + row * PAD + half * 64;
      float4* dst = (float4*)((f16*)Rh + (size_t)gr * 256 + hsel * 128 + half * 64);
      #pragma unroll
      for (int i = 0; i < 8; ++i)
        dst[i] = *(const float4*)(srcr + i * 8);
    }
  }
}

// ---------- kernel 2: per-edge fused relu + dot (fp16 table, 8-lane subgroups) ----------
__global__ __launch_bounds__(256) void edge_pass(
    const __half* __restrict__ Rh,
    const void*   __restrict__ pairs,
    const float*  __restrict__ b1,
    const float*  __restrict__ W2,
    const float*  __restrict__ b2,
    const int*    __restrict__ flag,
    float*        __restrict__ out)
{
  const int tid = threadIdx.x;
  const int ln  = tid & 7;                        // lane within 8-lane subgroup
  const int e   = blockIdx.x * 32 + (tid >> 3);   // one edge per subgroup
  const int is64 = *flag;

  long long u, v;
  if (is64) {
    const long long* q = (const long long*)pairs;
    u = q[2 * e]; v = q[2 * e + 1];
  } else {
    const int* q = (const int*)pairs;
    u = q[2 * e]; v = q[2 * e + 1];
  }

  const float4* Pu = (const float4*)(Rh + (size_t)u * 256 + ln * 16);
  const float4* Qv = (const float4*)(Rh + (size_t)v * 256 + 128 + ln * 16);
  float4 pu0 = Pu[0], pu1 = Pu[1];
  float4 qv0 = Qv[0], qv1 = Qv[1];

  const float4* b1p = (const float4*)(b1 + ln * 16);
  const float4* w2p = (const float4*)(W2 + ln * 16);
  float4 c0 = b1p[0], c1 = b1p[1], c2 = b1p[2], c3 = b1p[3];
  float4 w0 = w2p[0], w1 = w2p[1], w2_ = w2p[2], w3 = w2p[3];

  float s = 0.f;
  {
    float2 p, q;
    p = h2tof2(pu0.x); q = h2tof2(qv0.x);
    s = fmaf(fmaxf(p.x + q.x + c0.x, 0.f), w0.x, s);
    s = fmaf(fmaxf(p.y + q.y + c0.y, 0.f), w0.y, s);
    p = h2tof2(pu0.y); q = h2tof2(qv0.y);
    s = fmaf(fmaxf(p.x + q.x + c0.z, 0.f), w0.z, s);
    s = fmaf(fmaxf(p.y + q.y + c0.w, 0.f), w0.w, s);
    p = h2tof2(pu0.z); q = h2tof2(qv0.z);
    s = fmaf(fmaxf(p.x + q.x + c1.x, 0.f), w1.x, s);
    s = fmaf(fmaxf(p.y + q.y + c1.y, 0.f), w1.y, s);
    p = h2tof2(pu0.w); q = h2tof2(qv0.w);
    s = fmaf(fmaxf(p.x + q.x + c1.z, 0.f), w1.z, s);
    s = fmaf(fmaxf(p.y + q.y + c1.w, 0.f), w1.w, s);
    p = h2tof2(pu1.x); q = h2tof2(qv1.x);
    s = fmaf(fmaxf(p.x + q.x + c2.x, 0.f), w2_.x, s);
    s = fmaf(fmaxf(p.y + q.y + c2.y, 0.f), w2_.y, s);
    p = h2tof2(pu1.y); q = h2tof2(qv1.y);
    s = fmaf(fmaxf(p.x + q.x + c2.z, 0.f), w2_.z, s);
    s = fmaf(fmaxf(p.y + q.y + c2.w, 0.f), w2_.w, s);
    p = h2tof2(pu1.z); q = h2tof2(qv1.z);
    s = fmaf(fmaxf(p.x + q.x + c3.x, 0.f), w3.x, s);
    s = fmaf(fmaxf(p.y + q.y + c3.y, 0.f), w3.y, s);
    p = h2tof2(pu1.w); q = h2tof2(qv1.w);
    s = fmaf(fmaxf(p.x + q.x + c3.z, 0.f), w3.z, s);
    s = fmaf(fmaxf(p.y + q.y + c3.w, 0.f), w3.w, s);
  }

  s += __shfl_xor(s, 1);
  s += __shfl_xor(s, 2);
  s += __shfl_xor(s, 4);

  if (ln == 0) out[e] = s + b2[0];
}

// ---------- FALLBACK: round-1 fused kernel (used if ws too small) ----------
__global__ __launch_bounds__(256) void edge_mlp(
    const float* __restrict__ z,
    const void*  __restrict__ pairs,
    const float* __restrict__ W1,
    const float* __restrict__ b1,
    const float* __restrict__ W2,
    const float* __restrict__ b2,
    const int*   __restrict__ flag,
    float*       __restrict__ out)
{
  __shared__ __align__(16) float Asf[KT][BP];
  __shared__ __align__(16) float Bsf[KT][HIDDEN];

  const int tid = threadIdx.x;
  const int p0  = blockIdx.x * BP;
  const int is64 = *flag;

  const int sp   = tid >> 1;
  const int half = tid & 1;
  const int bk   = tid >> 3;
  const int bc   = (tid & 7) * 16;

  int uu = 0, vv = 0;
  {
    int gp = p0 + sp;
    if (gp < NPAIRS) {
      if (is64) {
        const long long* q = (const long long*)pairs;
        uu = (int)q[2 * gp];
        vv = (int)q[2 * gp + 1];
      } else {
        const int* q = (const int*)pairs;
        uu = q[2 * gp];
        vv = q[2 * gp + 1];
      }
    }
  }

  const int wave  = tid >> 6;
  const int lane  = tid & 63;
  const int pg    = lane >> 3;
  const int cg    = lane & 7;
  const int pbase = (wave >> 1) * 64 + pg * 8;
  const int cbase = (wave & 1)  * 64 + cg * 8;

  float acc[8][8];
  #pragma unroll
  for (int i = 0; i < 8; ++i)
    #pragma unroll
    for (int j = 0; j < 8; ++j) acc[i][j] = 0.f;

  for (int kt = 0; kt < 8; ++kt) {
    {
      const int node = (kt < 4) ? uu : vv;
      const int koff = (kt & 3) * 32 + half * 16;
      const float4* src = (const float4*)(z + (size_t)node * HIDDEN + koff);
      #pragma unroll
      for (int i = 0; i < 4; ++i) {
        float4 v4 = src[i];
        int tk = half * 16 + 4 * i;
        Asf[tk + 0][sp] = v4.x;
        Asf[tk + 1][sp] = v4.y;
        Asf[tk + 2][sp] = v4.z;
        Asf[tk + 3][sp] = v4.w;
      }
    }
    {
      const float4* src = (const float4*)(W1 + (size_t)(kt * KT + bk) * HIDDEN + bc);
      float4* dst = (float4*)&Bsf[bk][bc];
      #pragma unroll
      for (int i = 0; i < 4; ++i) dst[i] = src[i];
    }
    __syncthreads();

    #pragma unroll 8
    for (int k = 0; k < KT; ++k) {
      float4 a0  = *(const float4*)&Asf[k][pbase];
      float4 a1  = *(const float4*)&Asf[k][pbase + 4];
      float4 bb0 = *(const float4*)&Bsf[k][cbase];
      float4 bb1 = *(const float4*)&Bsf[k][cbase + 4];
      float av[8] = {a0.x, a0.y, a0.z, a0.w, a1.x, a1.y, a1.z, a1.w};
      float bv[8] = {bb0.x, bb0.y, bb0.z, bb0.w, bb1.x, bb1.y, bb1.z, bb1.w};
      #pragma unroll
      for (int i = 0; i < 8; ++i)
        #pragma unroll
        for (int j = 0; j < 8; ++j)
          acc[i][j] = fmaf(av[i], bv[j], acc[i][j]);
    }
    __syncthreads();
  }

  float b1v[8], w2v[8];
  #pragma unroll
  for (int j = 0; j < 8; ++j) {
    b1v[j] = b1[cbase + j];
    w2v[j] = W2[cbase + j];
  }
  float psum[8];
  #pragma unroll
  for (int i = 0; i < 8; ++i) {
    float s = 0.f;
    #pragma unroll
    for (int j = 0; j < 8; ++j) {
      float h = fmaxf(acc[i][j] + b1v[j], 0.f);
      s = fmaf(h, w2v[j], s);
    }
    psum[i] = s;
  }

  float* red = &Asf[0][0];
  const int cidx = (wave & 1) * 8 + cg;
  #pragma unroll
  for (int i = 0; i < 8; ++i) red[(pbase + i) * 16 + cidx] = psum[i];
  __syncthreads();

  if (tid < BP) {
    float s = b2[0];
    #pragma unroll
    for (int j = 0; j < 16; ++j) s += red[tid * 16 + j];
    int gp = p0 + tid;
    if (gp < NPAIRS) out[gp] = s;
  }
}

extern "C" void kernel_launch(void* const* d_in, const int* in_sizes, int n_in,
                              void* d_out, int out_size, void* d_ws, size_t ws_size,
                              hipStream_t stream) {
  const float* z     = (const float*)d_in[0];
  const void*  pairs =               d_in[1];
  const float* W1    = (const float*)d_in[2];
  const float* b1    = (const float*)d_in[3];
  const float* W2    = (const float*)d_in[4];
  const float* b2    = (const float*)d_in[5];
  float* out = (float*)d_out;

  const size_t R_BYTES   = (size_t)NUM_NODES * 256 * sizeof(__half);  // 51.2 MB
  const size_t W1T_BYTES = (size_t)2 * 128 * 128 * sizeof(f16);       // 64 KB

  if (ws_size >= R_BYTES + W1T_BYTES + 256) {
    __half* Rh  = (__half*)d_ws;
    f16*    W1t = (f16*)((char*)d_ws + R_BYTES);
    int*    flag = (int*)((char*)d_ws + R_BYTES + W1T_BYTES);
    transpose_w1<<<dim3(4, 4, 2), 256, 0, stream>>>(W1, W1t);
    detect_idx64<<<1, 64, 0, stream>>>((const unsigned int*)pairs, flag);
    dim3 grid1((NUM_NODES + 127) / 128, 2);
    node_precompute_mfma<<<grid1, 256, 0, stream>>>(z, W1t, Rh);
    edge_pass<<<NPAIRS / 32, 256, 0, stream>>>(Rh, pairs, b1, W2, b2, flag, out);
  } else {
    int* flag = (int*)d_ws;
    detect_idx64<<<1, 64, 0, stream>>>((const unsigned int*)pairs, flag);
    const int grid = (NPAIRS + BP - 1) / BP;
    edge_mlp<<<grid, 256, 0, stream>>>(z, pairs, W1, b1, W2, b2, flag, out);
  }
}